// Round 3
// baseline (1815.103 us; speedup 1.0000x reference)
//
#include <hip/hip_runtime.h>

// FeaStNet NeighbourAssignment, restructured:
//   ST[i][0:8]=s_i, ST[i][8:16]=t_i
//   Q[e][m] = softmax_m(s[dst[e]][m] + t[src[e]][m])
//   rowptr[i] = first edge e with dst[e] >= i   (dst sorted)
//   G[i][m][c] = sum_{e in seg(i)} Q[e][m] * x[src[e]][c]
//   R[i][m]    = sum_{e in seg(i)} Q[e][m]
//   out[i][o]  = (1/8) * ( sum_{m,c} G[i][m][c]*W[m][c][o] + sum_m R[i][m]*b[m][o] )

#define CDIM 64
#define SDIM 8

__global__ __launch_bounds__(256) void k0_rowptr(
    const int* __restrict__ dst, int* __restrict__ rowptr, int N, int E) {
  int e = blockIdx.x * 256 + threadIdx.x;
  if (e >= E) return;
  int a = dst[e];
  int bnd = (e + 1 < E) ? dst[e + 1] : N;
  if (e == 0) {
    for (int d = 0; d <= a; ++d) rowptr[d] = 0;
  }
  for (int d = a + 1; d <= bnd; ++d) rowptr[d] = e + 1;
}

__global__ __launch_bounds__(256) void k1_st(
    const float* __restrict__ x, const float* __restrict__ Ws,
    const float* __restrict__ bs, const float* __restrict__ Wt,
    const float* __restrict__ bt, float* __restrict__ ST, int N) {
  int tid = blockIdx.x * 256 + threadIdx.x;
  int i = tid >> 4, m = tid & 15;
  if (i >= N) return;
  int mm = m & 7;
  const float* Wp = (m < 8) ? Ws : Wt;
  float acc = (m < 8) ? bs[mm] : bt[mm];
  const float* xr = x + (size_t)i * CDIM;
#pragma unroll
  for (int c = 0; c < CDIM; ++c) acc += xr[c] * Wp[c * SDIM + mm];
  ST[i * 16 + m] = acc;
}

__global__ __launch_bounds__(256) void k2_q(
    const float* __restrict__ ST, const int* __restrict__ src,
    const int* __restrict__ dst, float* __restrict__ Q, int E) {
  int e = blockIdx.x * 256 + threadIdx.x;
  if (e >= E) return;
  int d = dst[e], j = src[e];
  const float* sd = ST + (size_t)d * 16;
  const float* tj = ST + (size_t)j * 16 + 8;
  float z[8];
  float mx = -1e30f;
#pragma unroll
  for (int m = 0; m < 8; ++m) {
    z[m] = sd[m] + tj[m];
    mx = fmaxf(mx, z[m]);
  }
  float sum = 0.f;
#pragma unroll
  for (int m = 0; m < 8; ++m) {
    z[m] = __expf(z[m] - mx);
    sum += z[m];
  }
  float inv = 1.0f / sum;
  float4* Qo = (float4*)(Q + (size_t)e * 8);
  Qo[0] = make_float4(z[0] * inv, z[1] * inv, z[2] * inv, z[3] * inv);
  Qo[1] = make_float4(z[4] * inv, z[5] * inv, z[6] * inv, z[7] * inv);
}

__global__ __launch_bounds__(256) void k3_gather(
    const float* __restrict__ x, const int* __restrict__ src,
    const int* __restrict__ rowptr, const float* __restrict__ Q,
    float* __restrict__ G, float* __restrict__ R, int N) {
  int wave = __builtin_amdgcn_readfirstlane(threadIdx.x >> 6);
  int lane = threadIdx.x & 63;
  int i = blockIdx.x * 4 + wave;
  if (i >= N) return;

  int lo = rowptr[i];
  int hi = rowptr[i + 1];

  float g[8] = {0, 0, 0, 0, 0, 0, 0, 0};
  float r[8] = {0, 0, 0, 0, 0, 0, 0, 0};

  int deg = hi - lo;
  int emain_end = lo + (deg & ~7);

  if (deg >= 8) {
    int idx[8];
#pragma unroll
    for (int k = 0; k < 8; ++k) idx[k] = src[lo + k];

    for (int e0 = lo; e0 < emain_end; e0 += 8) {
      // issue this batch's 8 x-gathers first (8 loads in flight)
      float xv[8];
#pragma unroll
      for (int k = 0; k < 8; ++k) xv[k] = x[(size_t)idx[k] * CDIM + lane];

      // prefetch next batch's indices while x-gathers are in flight
      int nidx[8];
      int nbase = (e0 + 8 < emain_end) ? (e0 + 8) : lo;
#pragma unroll
      for (int k = 0; k < 8; ++k) nidx[k] = src[nbase + k];

      // Q for the batch: 256 B contiguous, wave-uniform
#pragma unroll
      for (int k = 0; k < 8; ++k) {
        const float* q = Q + (size_t)(e0 + k) * 8;
#pragma unroll
        for (int m = 0; m < 8; ++m) {
          float qv = q[m];
          g[m] = fmaf(qv, xv[k], g[m]);
          r[m] += qv;
        }
      }
#pragma unroll
      for (int k = 0; k < 8; ++k) idx[k] = nidx[k];
    }
  }

  // tail (< 8 edges)
  for (int e = emain_end; e < hi; ++e) {
    int j = src[e];
    float xv = x[(size_t)j * CDIM + lane];
    const float* q = Q + (size_t)e * 8;
#pragma unroll
    for (int m = 0; m < 8; ++m) {
      float qv = q[m];
      g[m] = fmaf(qv, xv, g[m]);
      r[m] += qv;
    }
  }

  float* Gi = G + (size_t)i * 512;
#pragma unroll
  for (int m = 0; m < 8; ++m) Gi[m * 64 + lane] = g[m];
  if (lane == 0) {
    float* Ri = R + (size_t)i * 8;
#pragma unroll
    for (int m = 0; m < 8; ++m) Ri[m] = r[m];
  }
}

// k4 v3: wave-private LDS-staged skinny GEMM out = (G @ Wcat + R @ b) / 8
// Each wave owns 8 rows of G; K=512 processed in 8 chunks of 64.
// G chunk loads are coalesced float4, held in regs through compute, written
// to the alternate LDS buffer AFTER compute so the vmcnt drain is covered.
// Compute reads G via broadcast (wave-uniform) ds_read_b128 — conflict-free.
__global__ __launch_bounds__(256) void k4_gemm(
    const float* __restrict__ G, const float* __restrict__ R,
    const float* __restrict__ W, const float* __restrict__ b,
    float* __restrict__ out, int N) {
  __shared__ float lds[4][2][8][64];  // 16 KB: [wave][buf][row][k]
  int wave = threadIdx.x >> 6;
  int lane = threadIdx.x & 63;
  int i0 = (blockIdx.x * 4 + wave) * 8;
  if (i0 >= N) return;  // wave-private LDS, no barriers -> divergent exit OK

  int lr = lane >> 3;  // row within 8-row tile that this lane loads
  int lf = lane & 7;   // float4 index within half-chunk
  int grow = i0 + lr;
  grow = grow < N ? grow : N - 1;
  const float* gbase = G + (size_t)grow * 512;
  float* ldsw = &lds[wave][0][0][0];  // buffer stride = 512 floats

  float acc[8] = {0, 0, 0, 0, 0, 0, 0, 0};

  // prologue: chunk 0 -> buf 0
  {
    float4 u0 = *(const float4*)(gbase + lf * 4);
    float4 u1 = *(const float4*)(gbase + 32 + lf * 4);
    *(float4*)(ldsw + lr * 64 + lf * 4) = u0;
    *(float4*)(ldsw + lr * 64 + 32 + lf * 4) = u1;
  }

  for (int c = 0; c < 8; ++c) {
    int buf = c & 1;
    float4 n0, n1;
    if (c < 7) {  // issue next chunk's global loads before compute
      const float* gn = gbase + (c + 1) * 64;
      n0 = *(const float4*)(gn + lf * 4);
      n1 = *(const float4*)(gn + 32 + lf * 4);
    }

    const float* gl = ldsw + buf * 512;
    const float* Wk = W + (size_t)(c * 64) * 64 + lane;
#pragma unroll
    for (int kk = 0; kk < 64; kk += 8) {
      float w8[8];
#pragma unroll
      for (int t = 0; t < 8; ++t) w8[t] = Wk[(size_t)(kk + t) * 64];
#pragma unroll
      for (int r = 0; r < 8; ++r) {
        const float* gr = gl + r * 64 + kk;
        acc[r] = fmaf(gr[0], w8[0], acc[r]);
        acc[r] = fmaf(gr[1], w8[1], acc[r]);
        acc[r] = fmaf(gr[2], w8[2], acc[r]);
        acc[r] = fmaf(gr[3], w8[3], acc[r]);
        acc[r] = fmaf(gr[4], w8[4], acc[r]);
        acc[r] = fmaf(gr[5], w8[5], acc[r]);
        acc[r] = fmaf(gr[6], w8[6], acc[r]);
        acc[r] = fmaf(gr[7], w8[7], acc[r]);
      }
    }

    if (c < 7) {  // write prefetched chunk after compute (vmcnt drain here)
      float* ld2 = ldsw + (buf ^ 1) * 512;
      *(float4*)(ld2 + lr * 64 + lf * 4) = n0;
      *(float4*)(ld2 + lr * 64 + 32 + lf * 4) = n1;
    }
  }

#pragma unroll
  for (int r = 0; r < 8; ++r) {
    int ri = i0 + r;
    if (ri >= N) break;
    float a = acc[r];
    const float* Ri = R + (size_t)ri * 8;
#pragma unroll
    for (int m = 0; m < 8; ++m) a = fmaf(Ri[m], b[(size_t)m * 64 + lane], a);
    out[(size_t)ri * 64 + lane] = a * 0.125f;
  }
}

extern "C" void kernel_launch(void* const* d_in, const int* in_sizes, int n_in,
                              void* d_out, int out_size, void* d_ws, size_t ws_size,
                              hipStream_t stream) {
  const float* x  = (const float*)d_in[0];   // [N,64]
  const int* src  = (const int*)d_in[1];     // [E]
  const int* dst  = (const int*)d_in[2];     // [E] sorted
  const float* W  = (const float*)d_in[3];   // [8,64,64]
  const float* b  = (const float*)d_in[4];   // [8,64]
  const float* Ws = (const float*)d_in[5];   // [64,8]
  const float* bs = (const float*)d_in[6];   // [8]
  const float* Wt = (const float*)d_in[7];   // [64,8]
  const float* bt = (const float*)d_in[8];   // [8]
  int N = in_sizes[0] / CDIM;
  int E = in_sizes[1];
  float* out = (float*)d_out;

  float* ST = (float*)d_ws;                  // N*16 f32
  float* Q  = ST + (size_t)N * 16;           // E*8 f32
  float* G  = Q + (size_t)E * 8;             // N*512 f32
  float* R  = G + (size_t)N * 512;           // N*8 f32
  int* rowptr = (int*)(R + (size_t)N * 8);   // N+1 i32

  k0_rowptr<<<(E + 255) / 256, 256, 0, stream>>>(dst, rowptr, N, E);
  k1_st<<<(N * 16 + 255) / 256, 256, 0, stream>>>(x, Ws, bs, Wt, bt, ST, N);
  k2_q<<<(E + 255) / 256, 256, 0, stream>>>(ST, src, dst, Q, E);
  k3_gather<<<(N + 3) / 4, 256, 0, stream>>>(x, src, rowptr, Q, G, R, N);
  k4_gemm<<<(N + 31) / 32, 256, 0, stream>>>(G, R, W, b, out, N);
}

// Round 4
// 217.349 us; speedup vs baseline: 8.3511x; 8.3511x over previous
//
#include <hip/hip_runtime.h>
#include <hip/hip_bf16.h>

// FeaStNet NeighbourAssignment:
//   ST[i][0:8]=s_i, ST[i][8:16]=t_i
//   Q[e][m] = softmax_m(s[dst[e]][m] + t[src[e]][m])
//   rowptr[i] = first edge e with dst[e] >= i   (dst sorted)
//   Gbf[i][m*64+c] = bf16( sum_{e in seg(i)} Q[e][m] * x[src[e]][c] )
//   R[i][m]        = sum_{e in seg(i)} Q[e][m]
//   out[i][o]  = (1/8) * ( sum_k Gbf[i][k]*Wcat[k][o] + sum_m R[i][m]*b[m][o] )
// k4 does the [N,512]@[512,64] with bf16 MFMA (16x16x32), W^T staged in LDS.

#define CDIM 64
#define SDIM 8

typedef __bf16 bf16x8 __attribute__((ext_vector_type(8)));
typedef float f32x4 __attribute__((ext_vector_type(4)));

__global__ __launch_bounds__(256) void k0_rowptr(
    const int* __restrict__ dst, int* __restrict__ rowptr, int N, int E) {
  int e = blockIdx.x * 256 + threadIdx.x;
  if (e >= E) return;
  int a = dst[e];
  int bnd = (e + 1 < E) ? dst[e + 1] : N;
  if (e == 0) {
    for (int d = 0; d <= a; ++d) rowptr[d] = 0;
  }
  for (int d = a + 1; d <= bnd; ++d) rowptr[d] = e + 1;
}

__global__ __launch_bounds__(256) void k1_st(
    const float* __restrict__ x, const float* __restrict__ Ws,
    const float* __restrict__ bs, const float* __restrict__ Wt,
    const float* __restrict__ bt, float* __restrict__ ST, int N) {
  int tid = blockIdx.x * 256 + threadIdx.x;
  int i = tid >> 4, m = tid & 15;
  if (i >= N) return;
  int mm = m & 7;
  const float* Wp = (m < 8) ? Ws : Wt;
  float acc = (m < 8) ? bs[mm] : bt[mm];
  const float* xr = x + (size_t)i * CDIM;
#pragma unroll
  for (int c = 0; c < CDIM; ++c) acc += xr[c] * Wp[c * SDIM + mm];
  ST[i * 16 + m] = acc;
}

// Wcat[512][64] (= W[8][64][64]) -> WtB[64][512] bf16 (transposed)
__global__ __launch_bounds__(256) void k1b_wconv(
    const float* __restrict__ W, __hip_bfloat16* __restrict__ WtB) {
  int tid = blockIdx.x * 256 + threadIdx.x;
  if (tid >= 64 * 512) return;
  int o = tid >> 9, k = tid & 511;
  WtB[tid] = __float2bfloat16(W[(size_t)k * 64 + o]);
}

__global__ __launch_bounds__(256) void k2_q(
    const float* __restrict__ ST, const int* __restrict__ src,
    const int* __restrict__ dst, float* __restrict__ Q, int E) {
  int e = blockIdx.x * 256 + threadIdx.x;
  if (e >= E) return;
  int d = dst[e], j = src[e];
  const float* sd = ST + (size_t)d * 16;
  const float* tj = ST + (size_t)j * 16 + 8;
  float z[8];
  float mx = -1e30f;
#pragma unroll
  for (int m = 0; m < 8; ++m) {
    z[m] = sd[m] + tj[m];
    mx = fmaxf(mx, z[m]);
  }
  float sum = 0.f;
#pragma unroll
  for (int m = 0; m < 8; ++m) {
    z[m] = __expf(z[m] - mx);
    sum += z[m];
  }
  float inv = 1.0f / sum;
  float4* Qo = (float4*)(Q + (size_t)e * 8);
  Qo[0] = make_float4(z[0] * inv, z[1] * inv, z[2] * inv, z[3] * inv);
  Qo[1] = make_float4(z[4] * inv, z[5] * inv, z[6] * inv, z[7] * inv);
}

__global__ __launch_bounds__(256) void k3_gather(
    const float* __restrict__ x, const int* __restrict__ src,
    const int* __restrict__ rowptr, const float* __restrict__ Q,
    __hip_bfloat16* __restrict__ Gbf, float* __restrict__ R, int N) {
  int wave = __builtin_amdgcn_readfirstlane(threadIdx.x >> 6);
  int lane = threadIdx.x & 63;
  int i = blockIdx.x * 4 + wave;
  if (i >= N) return;

  int lo = rowptr[i];
  int hi = rowptr[i + 1];

  float g[8] = {0, 0, 0, 0, 0, 0, 0, 0};
  float r[8] = {0, 0, 0, 0, 0, 0, 0, 0};

  int deg = hi - lo;
  int emain_end = lo + (deg & ~7);

  if (deg >= 8) {
    int idx[8];
#pragma unroll
    for (int k = 0; k < 8; ++k) idx[k] = src[lo + k];

    for (int e0 = lo; e0 < emain_end; e0 += 8) {
      float xv[8];
#pragma unroll
      for (int k = 0; k < 8; ++k) xv[k] = x[(size_t)idx[k] * CDIM + lane];

      int nidx[8];
      int nbase = (e0 + 8 < emain_end) ? (e0 + 8) : lo;
#pragma unroll
      for (int k = 0; k < 8; ++k) nidx[k] = src[nbase + k];

#pragma unroll
      for (int k = 0; k < 8; ++k) {
        const float* q = Q + (size_t)(e0 + k) * 8;
#pragma unroll
        for (int m = 0; m < 8; ++m) {
          float qv = q[m];
          g[m] = fmaf(qv, xv[k], g[m]);
          r[m] += qv;
        }
      }
#pragma unroll
      for (int k = 0; k < 8; ++k) idx[k] = nidx[k];
    }
  }

  for (int e = emain_end; e < hi; ++e) {
    int j = src[e];
    float xv = x[(size_t)j * CDIM + lane];
    const float* q = Q + (size_t)e * 8;
#pragma unroll
    for (int m = 0; m < 8; ++m) {
      float qv = q[m];
      g[m] = fmaf(qv, xv, g[m]);
      r[m] += qv;
    }
  }

  __hip_bfloat16* Gi = Gbf + (size_t)i * 512;
#pragma unroll
  for (int m = 0; m < 8; ++m) Gi[m * 64 + lane] = __float2bfloat16(g[m]);
  if (lane == 0) {
    float* Ri = R + (size_t)i * 8;
#pragma unroll
    for (int m = 0; m < 8; ++m) Ri[m] = r[m];
  }
}

// out[N,64] = (Gbf[N,512] @ Wcat[512,64] + R[N,8] @ b[8,64]) / 8  via bf16 MFMA.
// WtB is Wcat transposed [64][512] bf16; staged in LDS with row stride 520
// (+8 pad -> <=2-way bank aliasing on ds_read_b128).
// Wave computes 16 rows x 64 cols: 4 C-frags, K-loop of 16 (k=32 each).
// Layouts (gfx950 16x16x32 bf16, learn_hip m89/m120-verified):
//   A: a[j] = A[lane&15][q*8+j], q=lane>>4
//   B: b[j] = B[q*8+j][lane&15]
//   D: reg v -> row=q*4+v, col=lane&15
__global__ __launch_bounds__(256) void k4_mfma(
    const __hip_bfloat16* __restrict__ Gbf, const float* __restrict__ R,
    const __hip_bfloat16* __restrict__ WtB, const float* __restrict__ bias,
    float* __restrict__ out, int N) {
  __shared__ float4 btile[64 * 65];  // [n][k] bf16, row = 520 bf16 = 65 float4
  {
    const float4* srcp = (const float4*)WtB;  // 4096 float4
    int t = threadIdx.x;
#pragma unroll
    for (int j = 0; j < 16; ++j) {
      int ci = t + j * 256;                       // chunk = 16B = 8 bf16
      btile[(ci >> 6) * 65 + (ci & 63)] = srcp[ci];
    }
  }
  __syncthreads();

  int wave = threadIdx.x >> 6;
  int lane = threadIdx.x & 63;
  int r0 = (blockIdx.x * 4 + wave) * 16;
  if (r0 >= N) return;

  int m = lane & 15;
  int q = lane >> 4;
  const __bf16* abase = (const __bf16*)(Gbf + (size_t)(r0 + m) * 512) + q * 8;
  const __bf16* lbase = (const __bf16*)btile + (size_t)m * 520 + q * 8;

  f32x4 acc0 = {0, 0, 0, 0}, acc1 = {0, 0, 0, 0};
  f32x4 acc2 = {0, 0, 0, 0}, acc3 = {0, 0, 0, 0};
#pragma unroll
  for (int kt = 0; kt < 16; ++kt) {
    bf16x8 a = *(const bf16x8*)(abase + kt * 32);
    bf16x8 b0 = *(const bf16x8*)(lbase + 0 * 520 + kt * 32);
    bf16x8 b1 = *(const bf16x8*)(lbase + 16 * 520 + kt * 32);
    bf16x8 b2 = *(const bf16x8*)(lbase + 32 * 520 + kt * 32);
    bf16x8 b3 = *(const bf16x8*)(lbase + 48 * 520 + kt * 32);
    acc0 = __builtin_amdgcn_mfma_f32_16x16x32_bf16(a, b0, acc0, 0, 0, 0);
    acc1 = __builtin_amdgcn_mfma_f32_16x16x32_bf16(a, b1, acc1, 0, 0, 0);
    acc2 = __builtin_amdgcn_mfma_f32_16x16x32_bf16(a, b2, acc2, 0, 0, 0);
    acc3 = __builtin_amdgcn_mfma_f32_16x16x32_bf16(a, b3, acc3, 0, 0, 0);
  }

#pragma unroll
  for (int v = 0; v < 4; ++v) {
    int ri = r0 + q * 4 + v;
    if (ri >= N) continue;
    const float* Ri = R + (size_t)ri * 8;
    float b0s = 0, b1s = 0, b2s = 0, b3s = 0;
#pragma unroll
    for (int mm = 0; mm < 8; ++mm) {
      float rv = Ri[mm];
      b0s = fmaf(rv, bias[mm * 64 + 0 + m], b0s);
      b1s = fmaf(rv, bias[mm * 64 + 16 + m], b1s);
      b2s = fmaf(rv, bias[mm * 64 + 32 + m], b2s);
      b3s = fmaf(rv, bias[mm * 64 + 48 + m], b3s);
    }
    float* orow = out + (size_t)ri * 64;
    orow[0 + m]  = (acc0[v] + b0s) * 0.125f;
    orow[16 + m] = (acc1[v] + b1s) * 0.125f;
    orow[32 + m] = (acc2[v] + b2s) * 0.125f;
    orow[48 + m] = (acc3[v] + b3s) * 0.125f;
  }
}

extern "C" void kernel_launch(void* const* d_in, const int* in_sizes, int n_in,
                              void* d_out, int out_size, void* d_ws, size_t ws_size,
                              hipStream_t stream) {
  const float* x  = (const float*)d_in[0];   // [N,64]
  const int* src  = (const int*)d_in[1];     // [E]
  const int* dst  = (const int*)d_in[2];     // [E] sorted
  const float* W  = (const float*)d_in[3];   // [8,64,64] == Wcat[512,64]
  const float* b  = (const float*)d_in[4];   // [8,64]
  const float* Ws = (const float*)d_in[5];   // [64,8]
  const float* bs = (const float*)d_in[6];   // [8]
  const float* Wt = (const float*)d_in[7];   // [64,8]
  const float* bt = (const float*)d_in[8];   // [8]
  int N = in_sizes[0] / CDIM;
  int E = in_sizes[1];
  float* out = (float*)d_out;

  float* ST = (float*)d_ws;                                  // N*16 f32
  float* Q  = ST + (size_t)N * 16;                           // E*8 f32
  __hip_bfloat16* Gbf = (__hip_bfloat16*)(Q + (size_t)E * 8);  // N*512 bf16
  float* R  = (float*)(Gbf + (size_t)N * 512);               // N*8 f32
  __hip_bfloat16* WtB = (__hip_bfloat16*)(R + (size_t)N * 8);  // 64*512 bf16
  int* rowptr = (int*)(WtB + 64 * 512);                      // N+1 i32

  k0_rowptr<<<(E + 255) / 256, 256, 0, stream>>>(dst, rowptr, N, E);
  k1_st<<<(N * 16 + 255) / 256, 256, 0, stream>>>(x, Ws, bs, Wt, bt, ST, N);
  k1b_wconv<<<128, 256, 0, stream>>>(W, WtB);
  k2_q<<<(E + 255) / 256, 256, 0, stream>>>(ST, src, dst, Q, E);
  k3_gather<<<(N + 3) / 4, 256, 0, stream>>>(x, src, rowptr, Q, Gbf, R, N);
  int mtiles = (N + 15) / 16;
  k4_mfma<<<(mtiles + 3) / 4, 256, 0, stream>>>(Gbf, R, WtB, b, out, N);
}

// Round 5
// 205.585 us; speedup vs baseline: 8.8290x; 1.0572x over previous
//
#include <hip/hip_runtime.h>
#include <hip/hip_bf16.h>

// FeaStNet NeighbourAssignment:
//   ST[i][0:8]=s_i, ST[i][8:16]=t_i ; xbf = bf16(x) ; WtB = bf16(Wcat^T)
//   Q[e][m] = softmax_m(s[dst[e]][m] + t[src[e]][m])   (+ rowptr build, fused)
//   Gbf[i][m*64+c] = bf16( sum_{e in seg(i)} Q[e][m] * xbf[src[e]][c] )
//   R[i][m]        = sum_{e in seg(i)} Q[e][m]
//   out = ( Gbf @ Wcat + R @ b ) / 8   via bf16 MFMA 16x16x32
// 4 launches: k1_pre, k2_q, k3_gather, k4_mfma.

#define CDIM 64
#define SDIM 8

typedef __bf16 bf16x8 __attribute__((ext_vector_type(8)));
typedef float f32x4 __attribute__((ext_vector_type(4)));

// blocks [0, nb1): ST + xbf ; blocks [nb1, nb1+128): Wcat^T -> bf16
__global__ __launch_bounds__(256) void k1_pre(
    const float* __restrict__ x, const float* __restrict__ Ws,
    const float* __restrict__ bs, const float* __restrict__ Wt,
    const float* __restrict__ bt, const float* __restrict__ W,
    float* __restrict__ ST, __hip_bfloat16* __restrict__ xbf,
    __hip_bfloat16* __restrict__ WtB, int N, int nb1) {
  if ((int)blockIdx.x >= nb1) {
    int t = ((int)blockIdx.x - nb1) * 256 + threadIdx.x;  // 0..32767
    int o = t >> 9, k = t & 511;
    WtB[t] = __float2bfloat16(W[(size_t)k * 64 + o]);
    return;
  }
  int tid = blockIdx.x * 256 + threadIdx.x;
  int i = tid >> 4, m = tid & 15;
  if (i >= N) return;
  int mm = m & 7;
  const float* Wp = (m < 8) ? Ws : Wt;
  float acc = (m < 8) ? bs[mm] : bt[mm];
  const float* xr = x + (size_t)i * CDIM;
#pragma unroll
  for (int c = 0; c < CDIM; ++c) acc += xr[c] * Wp[c * SDIM + mm];
  ST[i * 16 + m] = acc;
  // bf16 copy of x: thread m converts elements [4m, 4m+4) of row i
  float4 xv4 = *(const float4*)(xr + m * 4);
  union { __hip_bfloat16 h[4]; ushort4 u; } cv;
  cv.h[0] = __float2bfloat16(xv4.x);
  cv.h[1] = __float2bfloat16(xv4.y);
  cv.h[2] = __float2bfloat16(xv4.z);
  cv.h[3] = __float2bfloat16(xv4.w);
  *(ushort4*)(xbf + (size_t)i * CDIM + m * 4) = cv.u;
}

// Q softmax + rowptr build (dst sorted)
__global__ __launch_bounds__(256) void k2_q(
    const float* __restrict__ ST, const int* __restrict__ src,
    const int* __restrict__ dst, float* __restrict__ Q,
    int* __restrict__ rowptr, int N, int E) {
  int e = blockIdx.x * 256 + threadIdx.x;
  if (e >= E) return;
  int d = dst[e], j = src[e];
  int bnd = (e + 1 < E) ? dst[e + 1] : N;
  if (e == 0) {
    for (int dd = 0; dd <= d; ++dd) rowptr[dd] = 0;
  }
  for (int dd = d + 1; dd <= bnd; ++dd) rowptr[dd] = e + 1;

  const float* sd = ST + (size_t)d * 16;
  const float* tj = ST + (size_t)j * 16 + 8;
  float z[8];
  float mx = -1e30f;
#pragma unroll
  for (int m = 0; m < 8; ++m) {
    z[m] = sd[m] + tj[m];
    mx = fmaxf(mx, z[m]);
  }
  float sum = 0.f;
#pragma unroll
  for (int m = 0; m < 8; ++m) {
    z[m] = __expf(z[m] - mx);
    sum += z[m];
  }
  float inv = 1.0f / sum;
  float4* Qo = (float4*)(Q + (size_t)e * 8);
  Qo[0] = make_float4(z[0] * inv, z[1] * inv, z[2] * inv, z[3] * inv);
  Qo[1] = make_float4(z[4] * inv, z[5] * inv, z[6] * inv, z[7] * inv);
}

__global__ __launch_bounds__(256) void k3_gather(
    const __hip_bfloat16* __restrict__ xbf, const int* __restrict__ src,
    const int* __restrict__ rowptr, const float* __restrict__ Q,
    __hip_bfloat16* __restrict__ Gbf, float* __restrict__ R, int N) {
  int wave = __builtin_amdgcn_readfirstlane(threadIdx.x >> 6);
  int lane = threadIdx.x & 63;
  int i = blockIdx.x * 4 + wave;
  if (i >= N) return;

  int lo = rowptr[i];
  int hi = rowptr[i + 1];

  float g[8] = {0, 0, 0, 0, 0, 0, 0, 0};
  float r[8] = {0, 0, 0, 0, 0, 0, 0, 0};

  int deg = hi - lo;
  int emain_end = lo + (deg & ~7);

  if (deg >= 8) {
    int idx[8];
#pragma unroll
    for (int k = 0; k < 8; ++k) idx[k] = src[lo + k];

    for (int e0 = lo; e0 < emain_end; e0 += 8) {
      // 8 bf16 x-gathers in flight (128 B/wave each)
      float xv[8];
#pragma unroll
      for (int k = 0; k < 8; ++k)
        xv[k] = __bfloat162float(xbf[(size_t)idx[k] * CDIM + lane]);

      int nidx[8];
      int nbase = (e0 + 8 < emain_end) ? (e0 + 8) : lo;
#pragma unroll
      for (int k = 0; k < 8; ++k) nidx[k] = src[nbase + k];

#pragma unroll
      for (int k = 0; k < 8; ++k) {
        const float* q = Q + (size_t)(e0 + k) * 8;  // wave-uniform scalar loads
#pragma unroll
        for (int m = 0; m < 8; ++m) {
          float qv = q[m];
          g[m] = fmaf(qv, xv[k], g[m]);
          r[m] += qv;
        }
      }
#pragma unroll
      for (int k = 0; k < 8; ++k) idx[k] = nidx[k];
    }
  }

  for (int e = emain_end; e < hi; ++e) {
    int j = src[e];
    float xv = __bfloat162float(xbf[(size_t)j * CDIM + lane]);
    const float* q = Q + (size_t)e * 8;
#pragma unroll
    for (int m = 0; m < 8; ++m) {
      float qv = q[m];
      g[m] = fmaf(qv, xv, g[m]);
      r[m] += qv;
    }
  }

  __hip_bfloat16* Gi = Gbf + (size_t)i * 512;
#pragma unroll
  for (int m = 0; m < 8; ++m) Gi[m * 64 + lane] = __float2bfloat16(g[m]);
  if (lane == 0) {
    float* Ri = R + (size_t)i * 8;
#pragma unroll
    for (int m = 0; m < 8; ++m) Ri[m] = r[m];
  }
}

// out[N,64] = (Gbf[N,512] @ Wcat[512,64] + R[N,8] @ b[8,64]) / 8 via bf16 MFMA.
// WtB = Wcat^T [64][512] bf16, staged in LDS row-stride 520 (pad 8).
// Layouts (gfx950 16x16x32 bf16, m89/m120-verified):
//   A: a[j] = A[lane&15][q*8+j], q=lane>>4 ; B: b[j] = B[q*8+j][lane&15]
//   D: reg v -> row=q*4+v, col=lane&15
__global__ __launch_bounds__(256) void k4_mfma(
    const __hip_bfloat16* __restrict__ Gbf, const float* __restrict__ R,
    const __hip_bfloat16* __restrict__ WtB, const float* __restrict__ bias,
    float* __restrict__ out, int N) {
  __shared__ float4 btile[64 * 65];  // [n][k] bf16, row = 520 bf16 = 65 float4
  {
    const float4* srcp = (const float4*)WtB;  // 4096 float4
    int t = threadIdx.x;
#pragma unroll
    for (int j = 0; j < 16; ++j) {
      int ci = t + j * 256;
      btile[(ci >> 6) * 65 + (ci & 63)] = srcp[ci];
    }
  }
  __syncthreads();

  int wave = threadIdx.x >> 6;
  int lane = threadIdx.x & 63;
  int r0 = (blockIdx.x * 4 + wave) * 16;
  if (r0 >= N) return;

  int m = lane & 15;
  int q = lane >> 4;
  const __bf16* abase = (const __bf16*)(Gbf + (size_t)(r0 + m) * 512) + q * 8;
  const __bf16* lbase = (const __bf16*)btile + (size_t)m * 520 + q * 8;

  f32x4 acc0 = {0, 0, 0, 0}, acc1 = {0, 0, 0, 0};
  f32x4 acc2 = {0, 0, 0, 0}, acc3 = {0, 0, 0, 0};
#pragma unroll
  for (int kt = 0; kt < 16; ++kt) {
    bf16x8 a = *(const bf16x8*)(abase + kt * 32);
    bf16x8 b0 = *(const bf16x8*)(lbase + 0 * 520 + kt * 32);
    bf16x8 b1 = *(const bf16x8*)(lbase + 16 * 520 + kt * 32);
    bf16x8 b2 = *(const bf16x8*)(lbase + 32 * 520 + kt * 32);
    bf16x8 b3 = *(const bf16x8*)(lbase + 48 * 520 + kt * 32);
    acc0 = __builtin_amdgcn_mfma_f32_16x16x32_bf16(a, b0, acc0, 0, 0, 0);
    acc1 = __builtin_amdgcn_mfma_f32_16x16x32_bf16(a, b1, acc1, 0, 0, 0);
    acc2 = __builtin_amdgcn_mfma_f32_16x16x32_bf16(a, b2, acc2, 0, 0, 0);
    acc3 = __builtin_amdgcn_mfma_f32_16x16x32_bf16(a, b3, acc3, 0, 0, 0);
  }

#pragma unroll
  for (int v = 0; v < 4; ++v) {
    int ri = r0 + q * 4 + v;
    if (ri >= N) continue;
    const float* Ri = R + (size_t)ri * 8;
    float b0s = 0, b1s = 0, b2s = 0, b3s = 0;
#pragma unroll
    for (int mm = 0; mm < 8; ++mm) {
      float rv = Ri[mm];
      b0s = fmaf(rv, bias[mm * 64 + 0 + m], b0s);
      b1s = fmaf(rv, bias[mm * 64 + 16 + m], b1s);
      b2s = fmaf(rv, bias[mm * 64 + 32 + m], b2s);
      b3s = fmaf(rv, bias[mm * 64 + 48 + m], b3s);
    }
    float* orow = out + (size_t)ri * 64;
    orow[0 + m]  = (acc0[v] + b0s) * 0.125f;
    orow[16 + m] = (acc1[v] + b1s) * 0.125f;
    orow[32 + m] = (acc2[v] + b2s) * 0.125f;
    orow[48 + m] = (acc3[v] + b3s) * 0.125f;
  }
}

extern "C" void kernel_launch(void* const* d_in, const int* in_sizes, int n_in,
                              void* d_out, int out_size, void* d_ws, size_t ws_size,
                              hipStream_t stream) {
  const float* x  = (const float*)d_in[0];   // [N,64]
  const int* src  = (const int*)d_in[1];     // [E]
  const int* dst  = (const int*)d_in[2];     // [E] sorted
  const float* W  = (const float*)d_in[3];   // [8,64,64] == Wcat[512,64]
  const float* b  = (const float*)d_in[4];   // [8,64]
  const float* Ws = (const float*)d_in[5];   // [64,8]
  const float* bs = (const float*)d_in[6];   // [8]
  const float* Wt = (const float*)d_in[7];   // [64,8]
  const float* bt = (const float*)d_in[8];   // [8]
  int N = in_sizes[0] / CDIM;
  int E = in_sizes[1];
  float* out = (float*)d_out;

  float* ST = (float*)d_ws;                                    // N*16 f32
  float* Q  = ST + (size_t)N * 16;                             // E*8 f32
  __hip_bfloat16* Gbf = (__hip_bfloat16*)(Q + (size_t)E * 8);  // N*512 bf16
  float* R  = (float*)(Gbf + (size_t)N * 512);                 // N*8 f32
  __hip_bfloat16* WtB = (__hip_bfloat16*)(R + (size_t)N * 8);  // 64*512 bf16
  __hip_bfloat16* xbf = WtB + 64 * 512;                        // N*64 bf16
  int* rowptr = (int*)(xbf + (size_t)N * CDIM);                // N+1 i32

  int nb1 = (N * 16 + 255) / 256;
  k1_pre<<<nb1 + 128, 256, 0, stream>>>(x, Ws, bs, Wt, bt, W, ST, xbf, WtB, N, nb1);
  k2_q<<<(E + 255) / 256, 256, 0, stream>>>(ST, src, dst, Q, rowptr, N, E);
  k3_gather<<<(N + 3) / 4, 256, 0, stream>>>(xbf, src, rowptr, Q, Gbf, R, N);
  int mtiles = (N + 15) / 16;
  k4_mfma<<<(mtiles + 3) / 4, 256, 0, stream>>>(Gbf, R, WtB, b, out, N);
}

// Round 6
// 176.630 us; speedup vs baseline: 10.2763x; 1.1639x over previous
//
#include <hip/hip_runtime.h>
#include <hip/hip_bf16.h>

// FeaStNet NeighbourAssignment — 3 launches:
//   k1_pre : ST[i][0:8]=s_i, ST[i][8:16]=t_i ; xbf=bf16(x) ; WtB=bf16(Wcat^T) ;
//            rowptr from sorted dst
//   k3_fused: per node i (one wave): for each 8-edge batch, inline softmax
//            q[e][m]=softmax_m(s[i][m]+t[src[e]][m]) (8-lane groups, shfl),
//            Gbf[i][m][c] += q*xbf[src[e]][c], R[i][m]=sum q  (q via wave LDS)
//   k4_mfma: out = (Gbf @ Wcat + R @ b)/8 via bf16 MFMA 16x16x32

#define CDIM 64
#define SDIM 8

typedef __bf16 bf16x8 __attribute__((ext_vector_type(8)));
typedef float f32x4 __attribute__((ext_vector_type(4)));

// blocks [0,nb1): ST + xbf ; [nb1,nb1+128): WtB ; [nb1+128, +nbE): rowptr
__global__ __launch_bounds__(256) void k1_pre(
    const float* __restrict__ x, const float* __restrict__ Ws,
    const float* __restrict__ bs, const float* __restrict__ Wt,
    const float* __restrict__ bt, const float* __restrict__ W,
    const int* __restrict__ dst, float* __restrict__ ST,
    __hip_bfloat16* __restrict__ xbf, __hip_bfloat16* __restrict__ WtB,
    int* __restrict__ rowptr, int N, int E, int nb1) {
  int bid = blockIdx.x;
  if (bid >= nb1 + 128) {  // rowptr build (dst sorted)
    int e = (bid - nb1 - 128) * 256 + threadIdx.x;
    if (e >= E) return;
    int a = dst[e];
    int bnd = (e + 1 < E) ? dst[e + 1] : N;
    if (e == 0) {
      for (int d = 0; d <= a; ++d) rowptr[d] = 0;
    }
    for (int d = a + 1; d <= bnd; ++d) rowptr[d] = e + 1;
    return;
  }
  if (bid >= nb1) {  // Wcat[512][64] -> WtB[64][512] bf16
    int t = (bid - nb1) * 256 + threadIdx.x;  // 0..32767
    int o = t >> 9, k = t & 511;
    WtB[t] = __float2bfloat16(W[(size_t)k * 64 + o]);
    return;
  }
  int tid = bid * 256 + threadIdx.x;
  int i = tid >> 4, m = tid & 15;
  if (i >= N) return;
  int mm = m & 7;
  const float* Wp = (m < 8) ? Ws : Wt;
  float acc = (m < 8) ? bs[mm] : bt[mm];
  const float* xr = x + (size_t)i * CDIM;
#pragma unroll
  for (int c = 0; c < CDIM; ++c) acc += xr[c] * Wp[c * SDIM + mm];
  ST[i * 16 + m] = acc;
  float4 xv4 = *(const float4*)(xr + m * 4);
  union { __hip_bfloat16 h[4]; ushort4 u; } cv;
  cv.h[0] = __float2bfloat16(xv4.x);
  cv.h[1] = __float2bfloat16(xv4.y);
  cv.h[2] = __float2bfloat16(xv4.z);
  cv.h[3] = __float2bfloat16(xv4.w);
  *(ushort4*)(xbf + (size_t)i * CDIM + m * 4) = cv.u;
}

// One wave per node. 8-edge batches; lane -> (k=lane>>3, mm=lane&7).
__global__ __launch_bounds__(256) void k3_fused(
    const __hip_bfloat16* __restrict__ xbf, const int* __restrict__ src,
    const int* __restrict__ rowptr, const float* __restrict__ ST,
    __hip_bfloat16* __restrict__ Gbf, float* __restrict__ R, int N) {
  __shared__ float qlds[4][64];
  int wave = __builtin_amdgcn_readfirstlane(threadIdx.x >> 6);
  int lane = threadIdx.x & 63;
  int i = blockIdx.x * 4 + wave;
  if (i >= N) return;  // wave-private LDS, no barriers

  int lo = rowptr[i];
  int hi = rowptr[i + 1];
  int mm = lane & 7;
  int kk = lane >> 3;

  // s[i][mm] — wave-uniform row, per-lane element
  float sv = ST[i * 16 + mm];

  float g[8] = {0, 0, 0, 0, 0, 0, 0, 0};
  float racc = 0.f;
  float* qw = &qlds[wave][0];

  if (lo < hi) {
    int ecl = hi - 1;
    int ek = lo + kk;
    int iv = src[ek < ecl ? ek : ecl];  // this lane-group's edge src

    for (int e0 = lo; e0 < hi; e0 += 8) {
      // prefetch next batch's src indices
      int e0n = e0 + 8;
      int ekn = e0n + kk;
      int ivn = (e0n < hi) ? src[ekn < ecl ? ekn : ecl] : iv;

      // broadcast the 8 src indices for the x-gathers
      int j0 = __builtin_amdgcn_readlane(iv, 0);
      int j1 = __builtin_amdgcn_readlane(iv, 8);
      int j2 = __builtin_amdgcn_readlane(iv, 16);
      int j3 = __builtin_amdgcn_readlane(iv, 24);
      int j4 = __builtin_amdgcn_readlane(iv, 32);
      int j5 = __builtin_amdgcn_readlane(iv, 40);
      int j6 = __builtin_amdgcn_readlane(iv, 48);
      int j7 = __builtin_amdgcn_readlane(iv, 56);

      // t[src][mm] gather: 8 edges x 32B contiguous
      float tv = ST[iv * 16 + 8 + mm];

      // x-gathers (bf16 rows, 128B/wave each), 8 in flight
      float xv[8];
      xv[0] = __bfloat162float(xbf[(size_t)j0 * CDIM + lane]);
      xv[1] = __bfloat162float(xbf[(size_t)j1 * CDIM + lane]);
      xv[2] = __bfloat162float(xbf[(size_t)j2 * CDIM + lane]);
      xv[3] = __bfloat162float(xbf[(size_t)j3 * CDIM + lane]);
      xv[4] = __bfloat162float(xbf[(size_t)j4 * CDIM + lane]);
      xv[5] = __bfloat162float(xbf[(size_t)j5 * CDIM + lane]);
      xv[6] = __bfloat162float(xbf[(size_t)j6 * CDIM + lane]);
      xv[7] = __bfloat162float(xbf[(size_t)j7 * CDIM + lane]);

      // softmax over mm within each 8-lane group
      float z = sv + tv;
      float mx = fmaxf(z, __shfl_xor(z, 1));
      mx = fmaxf(mx, __shfl_xor(mx, 2));
      mx = fmaxf(mx, __shfl_xor(mx, 4));
      float ez = __expf(z - mx);
      float ssum = ez + __shfl_xor(ez, 1);
      ssum += __shfl_xor(ssum, 2);
      ssum += __shfl_xor(ssum, 4);
      float qv = ez * __frcp_rn(ssum);
      if (e0 + kk >= hi) qv = 0.f;  // padded slots contribute nothing
      racc += qv;
      qw[lane] = qv;  // stage for broadcast reads

#pragma unroll
      for (int k = 0; k < 8; ++k) {
        float4 qa = *(const float4*)(qw + k * 8);
        float4 qb = *(const float4*)(qw + k * 8 + 4);
        float xk = xv[k];
        g[0] = fmaf(qa.x, xk, g[0]);
        g[1] = fmaf(qa.y, xk, g[1]);
        g[2] = fmaf(qa.z, xk, g[2]);
        g[3] = fmaf(qa.w, xk, g[3]);
        g[4] = fmaf(qb.x, xk, g[4]);
        g[5] = fmaf(qb.y, xk, g[5]);
        g[6] = fmaf(qb.z, xk, g[6]);
        g[7] = fmaf(qb.w, xk, g[7]);
      }
      iv = ivn;
    }
  }

  __hip_bfloat16* Gi = Gbf + (size_t)i * 512;
#pragma unroll
  for (int m = 0; m < 8; ++m) Gi[m * 64 + lane] = __float2bfloat16(g[m]);

  // R[i][mm] = sum over k-groups of racc
  racc += __shfl_xor(racc, 8);
  racc += __shfl_xor(racc, 16);
  racc += __shfl_xor(racc, 32);
  if (lane < 8) R[(size_t)i * 8 + lane] = racc;
}

// out[N,64] = (Gbf[N,512] @ Wcat[512,64] + R[N,8] @ b[8,64]) / 8 via bf16 MFMA.
// Layouts (gfx950 16x16x32 bf16, m89/m120-verified):
//   A: a[j]=A[lane&15][q*8+j], q=lane>>4 ; B: b[j]=B[q*8+j][lane&15]
//   D: reg v -> row=q*4+v, col=lane&15
__global__ __launch_bounds__(256) void k4_mfma(
    const __hip_bfloat16* __restrict__ Gbf, const float* __restrict__ R,
    const __hip_bfloat16* __restrict__ WtB, const float* __restrict__ bias,
    float* __restrict__ out, int N) {
  __shared__ float4 btile[64 * 65];  // [n][k] bf16, row = 520 bf16 = 65 float4
  {
    const float4* srcp = (const float4*)WtB;  // 4096 float4
    int t = threadIdx.x;
#pragma unroll
    for (int j = 0; j < 16; ++j) {
      int ci = t + j * 256;
      btile[(ci >> 6) * 65 + (ci & 63)] = srcp[ci];
    }
  }
  __syncthreads();

  int wave = threadIdx.x >> 6;
  int lane = threadIdx.x & 63;
  int r0 = (blockIdx.x * 4 + wave) * 16;
  if (r0 >= N) return;

  int m = lane & 15;
  int q = lane >> 4;
  const __bf16* abase = (const __bf16*)(Gbf + (size_t)(r0 + m) * 512) + q * 8;
  const __bf16* lbase = (const __bf16*)btile + (size_t)m * 520 + q * 8;

  f32x4 acc0 = {0, 0, 0, 0}, acc1 = {0, 0, 0, 0};
  f32x4 acc2 = {0, 0, 0, 0}, acc3 = {0, 0, 0, 0};
#pragma unroll
  for (int kt = 0; kt < 16; ++kt) {
    bf16x8 a = *(const bf16x8*)(abase + kt * 32);
    bf16x8 b0 = *(const bf16x8*)(lbase + 0 * 520 + kt * 32);
    bf16x8 b1 = *(const bf16x8*)(lbase + 16 * 520 + kt * 32);
    bf16x8 b2 = *(const bf16x8*)(lbase + 32 * 520 + kt * 32);
    bf16x8 b3 = *(const bf16x8*)(lbase + 48 * 520 + kt * 32);
    acc0 = __builtin_amdgcn_mfma_f32_16x16x32_bf16(a, b0, acc0, 0, 0, 0);
    acc1 = __builtin_amdgcn_mfma_f32_16x16x32_bf16(a, b1, acc1, 0, 0, 0);
    acc2 = __builtin_amdgcn_mfma_f32_16x16x32_bf16(a, b2, acc2, 0, 0, 0);
    acc3 = __builtin_amdgcn_mfma_f32_16x16x32_bf16(a, b3, acc3, 0, 0, 0);
  }

#pragma unroll
  for (int v = 0; v < 4; ++v) {
    int ri = r0 + q * 4 + v;
    if (ri >= N) continue;
    const float* Ri = R + (size_t)ri * 8;
    float b0s = 0, b1s = 0, b2s = 0, b3s = 0;
#pragma unroll
    for (int mm = 0; mm < 8; ++mm) {
      float rv = Ri[mm];
      b0s = fmaf(rv, bias[mm * 64 + 0 + m], b0s);
      b1s = fmaf(rv, bias[mm * 64 + 16 + m], b1s);
      b2s = fmaf(rv, bias[mm * 64 + 32 + m], b2s);
      b3s = fmaf(rv, bias[mm * 64 + 48 + m], b3s);
    }
    float* orow = out + (size_t)ri * 64;
    orow[0 + m]  = (acc0[v] + b0s) * 0.125f;
    orow[16 + m] = (acc1[v] + b1s) * 0.125f;
    orow[32 + m] = (acc2[v] + b2s) * 0.125f;
    orow[48 + m] = (acc3[v] + b3s) * 0.125f;
  }
}

extern "C" void kernel_launch(void* const* d_in, const int* in_sizes, int n_in,
                              void* d_out, int out_size, void* d_ws, size_t ws_size,
                              hipStream_t stream) {
  const float* x  = (const float*)d_in[0];   // [N,64]
  const int* src  = (const int*)d_in[1];     // [E]
  const int* dst  = (const int*)d_in[2];     // [E] sorted
  const float* W  = (const float*)d_in[3];   // [8,64,64] == Wcat[512,64]
  const float* b  = (const float*)d_in[4];   // [8,64]
  const float* Ws = (const float*)d_in[5];   // [64,8]
  const float* bs = (const float*)d_in[6];   // [8]
  const float* Wt = (const float*)d_in[7];   // [64,8]
  const float* bt = (const float*)d_in[8];   // [8]
  int N = in_sizes[0] / CDIM;
  int E = in_sizes[1];
  float* out = (float*)d_out;

  float* ST = (float*)d_ws;                                    // N*16 f32
  __hip_bfloat16* Gbf = (__hip_bfloat16*)(ST + (size_t)N * 16);  // N*512 bf16
  float* R  = (float*)(Gbf + (size_t)N * 512);                 // N*8 f32
  __hip_bfloat16* WtB = (__hip_bfloat16*)(R + (size_t)N * 8);  // 64*512 bf16
  __hip_bfloat16* xbf = WtB + 64 * 512;                        // N*64 bf16
  int* rowptr = (int*)(xbf + (size_t)N * CDIM);                // N+1 i32

  int nb1 = (N * 16 + 255) / 256;
  int nbE = (E + 255) / 256;
  k1_pre<<<nb1 + 128 + nbE, 256, 0, stream>>>(x, Ws, bs, Wt, bt, W, dst, ST,
                                              xbf, WtB, rowptr, N, E, nb1);
  k3_fused<<<(N + 3) / 4, 256, 0, stream>>>(xbf, src, rowptr, ST, Gbf, R, N);
  int mtiles = (N + 15) / 16;
  k4_mfma<<<(mtiles + 3) / 4, 256, 0, stream>>>(Gbf, R, WtB, b, out, N);
}